// Round 1
// baseline (552.487 us; speedup 1.0000x reference)
//
#include <hip/hip_runtime.h>
#include <stdint.h>

typedef unsigned short u16;
typedef __bf16 bf16x8 __attribute__((ext_vector_type(8)));
typedef float f32x4 __attribute__((ext_vector_type(4)));

#define BB 4
#define SS 1024
#define DD 1024
#define HH 16
#define DHH 64
#define FF 4096
#define NEGV -1000000.0f

__device__ __forceinline__ u16 f2b(float f) {
    uint32_t u = __float_as_uint(f);
    u += 0x7fff + ((u >> 16) & 1);
    return (u16)(u >> 16);
}

// ---------------- fp32 -> bf16 convert (vectorized) ----------------
__global__ void cvt_bf16_kernel(const float* __restrict__ in, u16* __restrict__ out, int n4) {
    int i = blockIdx.x * blockDim.x + threadIdx.x;
    if (i >= n4) return;
    float4 v = reinterpret_cast<const float4*>(in)[i];
    ushort4 o;
    o.x = f2b(v.x); o.y = f2b(v.y); o.z = f2b(v.z); o.w = f2b(v.w);
    reinterpret_cast<ushort4*>(out)[i] = o;
}

// ---------------- weight transpose + convert: W[K][N] f32 -> Wt[N][K] bf16 ----------------
__global__ void wtrans_kernel(const float* __restrict__ W, u16* __restrict__ Wt, int K, int N) {
    __shared__ u16 t[32][33];
    int n0 = blockIdx.x * 32, k0 = blockIdx.y * 32;
    int tx = threadIdx.x, ty = threadIdx.y;
#pragma unroll
    for (int r = 0; r < 32; r += 8)
        t[ty + r][tx] = f2b(W[(size_t)(k0 + ty + r) * N + n0 + tx]);
    __syncthreads();
#pragma unroll
    for (int r = 0; r < 32; r += 8)
        Wt[(size_t)(n0 + ty + r) * K + k0 + tx] = t[tx][ty + r];
}

// ---------------- V transpose per head: V[B*S][D] -> VT[(b*H+h)*DH + d][S] ----------------
__global__ void vtrans_kernel(const u16* __restrict__ V, u16* __restrict__ VT) {
    __shared__ u16 t[32][33];
    int bh = blockIdx.z;
    int b = bh >> 4, h = bh & 15;
    int s0 = blockIdx.x * 32, d0 = blockIdx.y * 32;
    int tx = threadIdx.x, ty = threadIdx.y;
#pragma unroll
    for (int r = 0; r < 32; r += 8)
        t[ty + r][tx] = V[(size_t)(b * SS + s0 + ty + r) * DD + h * DHH + d0 + tx];
    __syncthreads();
#pragma unroll
    for (int r = 0; r < 32; r += 8)
        VT[(size_t)(bh * DHH + d0 + ty + r) * SS + s0 + tx] = t[tx][ty + r];
}

// ---------------- GEMM: C[M][N] = A[M][K] * Bt[N][K]^T + bias ----------------
// 128x128 tile, BK=64, 4 waves (2x2 of 64x64), mfma 16x16x32 bf16
template<bool OUT_BF16, bool RELU>
__global__ __launch_bounds__(256, 2) void gemm_bt_kernel(
    const u16* __restrict__ A, const u16* __restrict__ Bt,
    const float* __restrict__ bias, void* __restrict__ Cv,
    int M, int N, int K)
{
    __shared__ __attribute__((aligned(16))) u16 As[128][72];
    __shared__ __attribute__((aligned(16))) u16 Bs[128][72];
    const int tid = threadIdx.x;
    const int lane = tid & 63, wid = tid >> 6;
    const int wr = wid >> 1, wc = wid & 1;
    const int m0 = blockIdx.y * 128, n0 = blockIdx.x * 128;
    const int arow = lane & 15;
    const int kseg = (lane >> 4) * 8;
    const f32x4 z4 = {0.f, 0.f, 0.f, 0.f};

    f32x4 acc[4][4];
#pragma unroll
    for (int i = 0; i < 4; ++i)
#pragma unroll
        for (int j = 0; j < 4; ++j) acc[i][j] = z4;

    for (int kt = 0; kt < K; kt += 64) {
        __syncthreads();
#pragma unroll
        for (int i = 0; i < 4; ++i) {
            int c = tid + i * 256;
            int row = c >> 3, c8 = (c & 7) * 8;
            uint4 va = *reinterpret_cast<const uint4*>(&A[(size_t)(m0 + row) * K + kt + c8]);
            *reinterpret_cast<uint4*>(&As[row][c8]) = va;
            uint4 vb = *reinterpret_cast<const uint4*>(&Bt[(size_t)(n0 + row) * K + kt + c8]);
            *reinterpret_cast<uint4*>(&Bs[row][c8]) = vb;
        }
        __syncthreads();
#pragma unroll
        for (int ks = 0; ks < 2; ++ks) {
            bf16x8 af[4], bfr[4];
#pragma unroll
            for (int mi = 0; mi < 4; ++mi)
                af[mi] = *reinterpret_cast<const bf16x8*>(&As[wr * 64 + mi * 16 + arow][ks * 32 + kseg]);
#pragma unroll
            for (int ni = 0; ni < 4; ++ni)
                bfr[ni] = *reinterpret_cast<const bf16x8*>(&Bs[wc * 64 + ni * 16 + arow][ks * 32 + kseg]);
#pragma unroll
            for (int mi = 0; mi < 4; ++mi)
#pragma unroll
                for (int ni = 0; ni < 4; ++ni)
                    acc[mi][ni] = __builtin_amdgcn_mfma_f32_16x16x32_bf16(af[mi], bfr[ni], acc[mi][ni], 0, 0, 0);
        }
    }
    // epilogue
    const int rrow = (lane >> 4) * 4;
#pragma unroll
    for (int mi = 0; mi < 4; ++mi) {
#pragma unroll
        for (int ni = 0; ni < 4; ++ni) {
            int col = n0 + wc * 64 + ni * 16 + arow;
            float bv = bias[col];
#pragma unroll
            for (int r = 0; r < 4; ++r) {
                int row = m0 + wr * 64 + mi * 16 + rrow + r;
                float v = acc[mi][ni][r] + bv;
                if (RELU) v = fmaxf(v, 0.f);
                if (OUT_BF16) ((u16*)Cv)[(size_t)row * N + col] = f2b(v);
                else          ((float*)Cv)[(size_t)row * N + col] = v;
            }
        }
    }
}

// ---------------- flash attention ----------------
// grid: (S/128, B*H); 256 threads = 4 waves; each wave owns 32 q-rows.
// Q[B*S][D] bf16 (head h at cols h*64..), K same, VT[(b*H+h)*64 + d][S] bf16.
// causal=1: keep k<=q ; causal=0: keep k < vlens[b]
__global__ __launch_bounds__(256, 2) void flash_attn_kernel(
    const u16* __restrict__ Q, const u16* __restrict__ K, const u16* __restrict__ VT,
    u16* __restrict__ O, const int* __restrict__ vlens, int causal)
{
    __shared__ __attribute__((aligned(16))) u16 Ks[128][72];
    __shared__ __attribute__((aligned(16))) u16 Vs[64][136];
    __shared__ __attribute__((aligned(16))) u16 Ps[128][136];
    const int tid = threadIdx.x, lane = tid & 63, wid = tid >> 6;
    const int qb = blockIdx.x, bh = blockIdx.y;
    const int b = bh >> 4, h = bh & 15;
    const int q0 = qb * 128;
    const int arow = lane & 15;
    const int kseg = (lane >> 4) * 8;
    const int rrow = (lane >> 4) * 4;
    const f32x4 z4 = {0.f, 0.f, 0.f, 0.f};

    // Q fragments (registers, per-wave 32 rows x 64 d)
    bf16x8 qf[2][2];
#pragma unroll
    for (int mi = 0; mi < 2; ++mi)
#pragma unroll
        for (int ks = 0; ks < 2; ++ks)
            qf[mi][ks] = *reinterpret_cast<const bf16x8*>(
                &Q[(size_t)(b * SS + q0 + wid * 32 + mi * 16 + arow) * DD + h * DHH + ks * 32 + kseg]);

    float m_run[2][4], l_run[2][4];
    f32x4 o[2][4];
#pragma unroll
    for (int mi = 0; mi < 2; ++mi) {
#pragma unroll
        for (int r = 0; r < 4; ++r) { m_run[mi][r] = -3e38f; l_run[mi][r] = 0.f; }
#pragma unroll
        for (int nd = 0; nd < 4; ++nd) o[mi][nd] = z4;
    }

    int vl = causal ? SS : vlens[b];
    int ntiles = causal ? (qb + 1) : ((vl + 127) >> 7);

    for (int kt = 0; kt < ntiles; ++kt) {
        const int kv0 = kt * 128;
        __syncthreads();
        // stage K tile [128 kv][64 d] and V tile [64 d][128 kv]
#pragma unroll
        for (int i = 0; i < 4; ++i) {
            int c = tid + i * 256;
            {
                int r = c >> 3, c8 = (c & 7) * 8;
                *reinterpret_cast<uint4*>(&Ks[r][c8]) =
                    *reinterpret_cast<const uint4*>(&K[(size_t)(b * SS + kv0 + r) * DD + h * DHH + c8]);
            }
            {
                int d = c >> 4, s8 = (c & 15) * 8;
                *reinterpret_cast<uint4*>(&Vs[d][s8]) =
                    *reinterpret_cast<const uint4*>(&VT[(size_t)(bh * DHH + d) * SS + kv0 + s8]);
            }
        }
        __syncthreads();

        // S = Q K^T
        f32x4 s[2][8];
#pragma unroll
        for (int mi = 0; mi < 2; ++mi)
#pragma unroll
            for (int ni = 0; ni < 8; ++ni) s[mi][ni] = z4;
#pragma unroll
        for (int ks = 0; ks < 2; ++ks) {
            bf16x8 kf[8];
#pragma unroll
            for (int ni = 0; ni < 8; ++ni)
                kf[ni] = *reinterpret_cast<const bf16x8*>(&Ks[ni * 16 + arow][ks * 32 + kseg]);
#pragma unroll
            for (int mi = 0; mi < 2; ++mi)
#pragma unroll
                for (int ni = 0; ni < 8; ++ni)
                    s[mi][ni] = __builtin_amdgcn_mfma_f32_16x16x32_bf16(qf[mi][ks], kf[ni], s[mi][ni], 0, 0, 0);
        }

        // scale + mask
        bool domask = causal ? (kt == qb) : (kv0 + 128 > vl);
#pragma unroll
        for (int mi = 0; mi < 2; ++mi)
#pragma unroll
            for (int ni = 0; ni < 8; ++ni)
#pragma unroll
                for (int r = 0; r < 4; ++r) {
                    float v = s[mi][ni][r] * 0.125f;
                    if (domask) {
                        int rg = q0 + wid * 32 + mi * 16 + rrow + r;
                        int cg = kv0 + ni * 16 + arow;
                        bool keep = causal ? (cg <= rg) : (cg < vl);
                        if (!keep) v = NEGV;
                    }
                    s[mi][ni][r] = v;
                }

        // online softmax
        float corr[2][4];
#pragma unroll
        for (int mi = 0; mi < 2; ++mi)
#pragma unroll
            for (int r = 0; r < 4; ++r) {
                float tm = -3e38f;
#pragma unroll
                for (int ni = 0; ni < 8; ++ni) tm = fmaxf(tm, s[mi][ni][r]);
#pragma unroll
                for (int off = 1; off < 16; off <<= 1) tm = fmaxf(tm, __shfl_xor(tm, off));
                float nm = fmaxf(m_run[mi][r], tm);
                float cr = __expf(m_run[mi][r] - nm);
                m_run[mi][r] = nm;
                corr[mi][r] = cr;
                float rs = 0.f;
#pragma unroll
                for (int ni = 0; ni < 8; ++ni) {
                    float p = __expf(s[mi][ni][r] - nm);
                    s[mi][ni][r] = p;
                    rs += p;
                }
#pragma unroll
                for (int off = 1; off < 16; off <<= 1) rs += __shfl_xor(rs, off);
                l_run[mi][r] = l_run[mi][r] * cr + rs;
            }
        // rescale O
#pragma unroll
        for (int mi = 0; mi < 2; ++mi)
#pragma unroll
            for (int nd = 0; nd < 4; ++nd)
#pragma unroll
                for (int r = 0; r < 4; ++r) o[mi][nd][r] *= corr[mi][r];

        // write P (bf16) to LDS (wave-private rows)
#pragma unroll
        for (int mi = 0; mi < 2; ++mi)
#pragma unroll
            for (int ni = 0; ni < 8; ++ni)
#pragma unroll
                for (int r = 0; r < 4; ++r)
                    Ps[wid * 32 + mi * 16 + rrow + r][ni * 16 + arow] = f2b(s[mi][ni][r]);

        // O += P V
#pragma unroll
        for (int kf_ = 0; kf_ < 4; ++kf_) {
            bf16x8 pa[2], vb[4];
#pragma unroll
            for (int mi = 0; mi < 2; ++mi)
                pa[mi] = *reinterpret_cast<const bf16x8*>(&Ps[wid * 32 + mi * 16 + arow][kf_ * 32 + kseg]);
#pragma unroll
            for (int nd = 0; nd < 4; ++nd)
                vb[nd] = *reinterpret_cast<const bf16x8*>(&Vs[nd * 16 + arow][kf_ * 32 + kseg]);
#pragma unroll
            for (int mi = 0; mi < 2; ++mi)
#pragma unroll
                for (int nd = 0; nd < 4; ++nd)
                    o[mi][nd] = __builtin_amdgcn_mfma_f32_16x16x32_bf16(pa[mi], vb[nd], o[mi][nd], 0, 0, 0);
        }
    }

    // epilogue: O /= l, write bf16
#pragma unroll
    for (int mi = 0; mi < 2; ++mi)
#pragma unroll
        for (int r = 0; r < 4; ++r) {
            float inv = 1.f / l_run[mi][r];
            int row = q0 + wid * 32 + mi * 16 + rrow + r;
#pragma unroll
            for (int nd = 0; nd < 4; ++nd)
                O[(size_t)(b * SS + row) * DD + h * DHH + nd * 16 + arow] = f2b(o[mi][nd][r] * inv);
        }
}

// ---------------- fused add + LayerNorm ----------------
// out32 = LN(A + R) (fp32), out16 = bf16 copy (optional)
__global__ void add_ln_kernel(const float* __restrict__ A, const float* __restrict__ R,
                              const float* __restrict__ g, const float* __restrict__ be,
                              float* __restrict__ out32, u16* __restrict__ out16)
{
    __shared__ float red[4][2];
    const int row = blockIdx.x, tid = threadIdx.x;
    const size_t base = (size_t)row * DD;
    float4 va = *reinterpret_cast<const float4*>(A + base + tid * 4);
    float4 vr = *reinterpret_cast<const float4*>(R + base + tid * 4);
    float x0 = va.x + vr.x, x1 = va.y + vr.y, x2 = va.z + vr.z, x3 = va.w + vr.w;
    float s = x0 + x1 + x2 + x3;
    float q = x0 * x0 + x1 * x1 + x2 * x2 + x3 * x3;
#pragma unroll
    for (int off = 32; off; off >>= 1) {
        s += __shfl_xor(s, off);
        q += __shfl_xor(q, off);
    }
    if ((tid & 63) == 0) { red[tid >> 6][0] = s; red[tid >> 6][1] = q; }
    __syncthreads();
    s = red[0][0] + red[1][0] + red[2][0] + red[3][0];
    q = red[0][1] + red[1][1] + red[2][1] + red[3][1];
    float mean = s * (1.f / 1024.f);
    float var = q * (1.f / 1024.f) - mean * mean;
    float rstd = rsqrtf(var + 1e-5f);
    int c = tid * 4;
    float o0 = (x0 - mean) * rstd * g[c + 0] + be[c + 0];
    float o1 = (x1 - mean) * rstd * g[c + 1] + be[c + 1];
    float o2 = (x2 - mean) * rstd * g[c + 2] + be[c + 2];
    float o3 = (x3 - mean) * rstd * g[c + 3] + be[c + 3];
    float4 ov = {o0, o1, o2, o3};
    *reinterpret_cast<float4*>(out32 + base + c) = ov;
    if (out16) {
        ushort4 hv;
        hv.x = f2b(o0); hv.y = f2b(o1); hv.z = f2b(o2); hv.w = f2b(o3);
        *reinterpret_cast<ushort4*>(out16 + base + c) = hv;
    }
}

extern "C" void kernel_launch(void* const* d_in, const int* in_sizes, int n_in,
                              void* d_out, int out_size, void* d_ws, size_t ws_size,
                              hipStream_t stream)
{
    const float* X   = (const float*)d_in[0];
    const float* ENC = (const float*)d_in[1];
    const int*   VL  = (const int*)d_in[2];
    const float* Wq1 = (const float*)d_in[3];  const float* bq1 = (const float*)d_in[4];
    const float* Wk1 = (const float*)d_in[5];  const float* bk1 = (const float*)d_in[6];
    const float* Wv1 = (const float*)d_in[7];  const float* bv1 = (const float*)d_in[8];
    const float* Wo1 = (const float*)d_in[9];  const float* bo1 = (const float*)d_in[10];
    const float* g1  = (const float*)d_in[11]; const float* be1 = (const float*)d_in[12];
    const float* Wq2 = (const float*)d_in[13]; const float* bq2 = (const float*)d_in[14];
    const float* Wk2 = (const float*)d_in[15]; const float* bk2 = (const float*)d_in[16];
    const float* Wv2 = (const float*)d_in[17]; const float* bv2 = (const float*)d_in[18];
    const float* Wo2 = (const float*)d_in[19]; const float* bo2 = (const float*)d_in[20];
    const float* g2  = (const float*)d_in[21]; const float* be2 = (const float*)d_in[22];
    const float* Wf1 = (const float*)d_in[23]; const float* bf1 = (const float*)d_in[24];
    const float* Wf2 = (const float*)d_in[25]; const float* bf2 = (const float*)d_in[26];
    const float* g3  = (const float*)d_in[27]; const float* be3 = (const float*)d_in[28];

    char* ws = (char*)d_ws;
    const size_t MB = 1024 * 1024;
    u16*   XBF  = (u16*)(ws + 0 * MB);    // 8MB
    u16*   ENCB = (u16*)(ws + 8 * MB);    // 8MB
    u16*   WT   = (u16*)(ws + 16 * MB);   // 8MB (reused for every weight)
    u16*   Qb   = (u16*)(ws + 24 * MB);   // 8MB
    u16*   Kb   = (u16*)(ws + 32 * MB);   // 8MB
    u16*   Vb   = (u16*)(ws + 40 * MB);   // 8MB
    u16*   VTb  = (u16*)(ws + 48 * MB);   // 8MB
    u16*   AO   = (u16*)(ws + 56 * MB);   // 8MB
    float* P32  = (float*)(ws + 64 * MB); // 16MB
    float* Y32  = (float*)(ws + 80 * MB); // 16MB
    u16*   YBF  = (u16*)(ws + 96 * MB);   // 8MB
    float* Z32  = (float*)(ws + 104 * MB);// 16MB
    u16*   ZBF  = (u16*)(ws + 120 * MB);  // 8MB
    u16*   HF   = (u16*)(ws + 128 * MB);  // 32MB -> 160MB total
    (void)ws_size; (void)in_sizes; (void)n_in; (void)out_size;

    const int M = BB * SS; // 4096

    // converts
    cvt_bf16_kernel<<<M * DD / 4 / 256, 256, 0, stream>>>(X, XBF, M * DD / 4);
    cvt_bf16_kernel<<<M * DD / 4 / 256, 256, 0, stream>>>(ENC, ENCB, M * DD / 4);

    // ---------- self attention ----------
    wtrans_kernel<<<dim3(DD / 32, DD / 32), dim3(32, 8), 0, stream>>>(Wq1, WT, DD, DD);
    gemm_bt_kernel<true, false><<<dim3(8, 32), 256, 0, stream>>>(XBF, WT, bq1, Qb, M, DD, DD);
    wtrans_kernel<<<dim3(DD / 32, DD / 32), dim3(32, 8), 0, stream>>>(Wk1, WT, DD, DD);
    gemm_bt_kernel<true, false><<<dim3(8, 32), 256, 0, stream>>>(XBF, WT, bk1, Kb, M, DD, DD);
    wtrans_kernel<<<dim3(DD / 32, DD / 32), dim3(32, 8), 0, stream>>>(Wv1, WT, DD, DD);
    gemm_bt_kernel<true, false><<<dim3(8, 32), 256, 0, stream>>>(XBF, WT, bv1, Vb, M, DD, DD);
    vtrans_kernel<<<dim3(32, 2, 64), dim3(32, 8), 0, stream>>>(Vb, VTb);
    flash_attn_kernel<<<dim3(8, 64), 256, 0, stream>>>(Qb, Kb, VTb, AO, VL, 1);
    wtrans_kernel<<<dim3(DD / 32, DD / 32), dim3(32, 8), 0, stream>>>(Wo1, WT, DD, DD);
    gemm_bt_kernel<false, false><<<dim3(8, 32), 256, 0, stream>>>(AO, WT, bo1, P32, M, DD, DD);
    add_ln_kernel<<<M, 256, 0, stream>>>(P32, X, g1, be1, Y32, YBF);

    // ---------- cross attention ----------
    wtrans_kernel<<<dim3(DD / 32, DD / 32), dim3(32, 8), 0, stream>>>(Wq2, WT, DD, DD);
    gemm_bt_kernel<true, false><<<dim3(8, 32), 256, 0, stream>>>(YBF, WT, bq2, Qb, M, DD, DD);
    wtrans_kernel<<<dim3(DD / 32, DD / 32), dim3(32, 8), 0, stream>>>(Wk2, WT, DD, DD);
    gemm_bt_kernel<true, false><<<dim3(8, 32), 256, 0, stream>>>(ENCB, WT, bk2, Kb, M, DD, DD);
    wtrans_kernel<<<dim3(DD / 32, DD / 32), dim3(32, 8), 0, stream>>>(Wv2, WT, DD, DD);
    gemm_bt_kernel<true, false><<<dim3(8, 32), 256, 0, stream>>>(ENCB, WT, bv2, Vb, M, DD, DD);
    vtrans_kernel<<<dim3(32, 2, 64), dim3(32, 8), 0, stream>>>(Vb, VTb);
    flash_attn_kernel<<<dim3(8, 64), 256, 0, stream>>>(Qb, Kb, VTb, AO, VL, 0);
    wtrans_kernel<<<dim3(DD / 32, DD / 32), dim3(32, 8), 0, stream>>>(Wo2, WT, DD, DD);
    gemm_bt_kernel<false, false><<<dim3(8, 32), 256, 0, stream>>>(AO, WT, bo2, P32, M, DD, DD);
    add_ln_kernel<<<M, 256, 0, stream>>>(P32, Y32, g2, be2, Z32, ZBF);

    // ---------- FFN ----------
    wtrans_kernel<<<dim3(FF / 32, DD / 32), dim3(32, 8), 0, stream>>>(Wf1, WT, DD, FF);
    gemm_bt_kernel<true, true><<<dim3(32, 32), 256, 0, stream>>>(ZBF, WT, bf1, HF, M, FF, DD);
    wtrans_kernel<<<dim3(DD / 32, FF / 32), dim3(32, 8), 0, stream>>>(Wf2, WT, FF, DD);
    gemm_bt_kernel<false, false><<<dim3(8, 32), 256, 0, stream>>>(HF, WT, bf2, P32, M, DD, FF);
    add_ln_kernel<<<M, 256, 0, stream>>>(P32, Z32, g3, be3, (float*)d_out, nullptr);
}

// Round 2
// 421.118 us; speedup vs baseline: 1.3120x; 1.3120x over previous
//
#include <hip/hip_runtime.h>
#include <stdint.h>

typedef unsigned short u16;
typedef __bf16 bf16x8 __attribute__((ext_vector_type(8)));
typedef float f32x4 __attribute__((ext_vector_type(4)));

#define BB 4
#define SS 1024
#define DD 1024
#define HH 16
#define DHH 64
#define FF 4096
#define NEGV -1000000.0f

__device__ __forceinline__ u16 f2b(float f) {
    uint32_t u = __float_as_uint(f);
    u += 0x7fff + ((u >> 16) & 1);
    return (u16)(u >> 16);
}

// async global->LDS, 16B per lane. LDS dest is wave-uniform base + lane*16
// (m104/m108); global src is per-lane. CK-style addrspace casts.
__device__ __forceinline__ void async16(const void* gp, void* lp) {
    auto g = reinterpret_cast<const __attribute__((address_space(1))) uint32_t*>(
        reinterpret_cast<uintptr_t>(gp));
    auto l = reinterpret_cast<__attribute__((address_space(3))) uint32_t*>(
        reinterpret_cast<uintptr_t>(lp));
    __builtin_amdgcn_global_load_lds(g, l, 16, 0, 0);
}

// ---------------- fp32 -> bf16 convert ----------------
__global__ void cvt_bf16_kernel(const float* __restrict__ in, u16* __restrict__ out, int n4) {
    int i = blockIdx.x * blockDim.x + threadIdx.x;
    if (i >= n4) return;
    float4 v = reinterpret_cast<const float4*>(in)[i];
    ushort4 o;
    o.x = f2b(v.x); o.y = f2b(v.y); o.z = f2b(v.z); o.w = f2b(v.w);
    reinterpret_cast<ushort4*>(out)[i] = o;
}

// ---------------- bias concat (for fused QKV / KV projections) ----------------
__global__ void concat_bias_kernel(const float* __restrict__ a, const float* __restrict__ b,
                                   const float* __restrict__ c, float* __restrict__ out) {
    int i = blockIdx.x * 256 + threadIdx.x;
    float v;
    if (i < 1024) v = a[i];
    else if (i < 2048) v = b[i - 1024];
    else v = c[i - 2048];
    out[i] = v;
}

// ---------------- weight transpose + convert: W[K][N] f32 -> Wt[N][K] bf16 ----------------
__global__ void wtrans_kernel(const float* __restrict__ W, u16* __restrict__ Wt, int K, int N) {
    __shared__ u16 t[32][33];
    int n0 = blockIdx.x * 32, k0 = blockIdx.y * 32;
    int tx = threadIdx.x, ty = threadIdx.y;
#pragma unroll
    for (int r = 0; r < 32; r += 8)
        t[ty + r][tx] = f2b(W[(size_t)(k0 + ty + r) * N + n0 + tx]);
    __syncthreads();
#pragma unroll
    for (int r = 0; r < 32; r += 8)
        Wt[(size_t)(n0 + ty + r) * K + k0 + tx] = t[tx][ty + r];
}

// ---------------- V transpose per head: V[(b*S+s)][ldv] cols h*64.. -> VT[(bh*64+d)][S] ----------------
__global__ void vtrans_kernel(const u16* __restrict__ V, int ldv, u16* __restrict__ VT) {
    __shared__ u16 t[32][33];
    int bh = blockIdx.z;
    int b = bh >> 4, h = bh & 15;
    int s0 = blockIdx.x * 32, d0 = blockIdx.y * 32;
    int tx = threadIdx.x, ty = threadIdx.y;
#pragma unroll
    for (int r = 0; r < 32; r += 8)
        t[ty + r][tx] = V[(size_t)(b * SS + s0 + ty + r) * ldv + h * DHH + d0 + tx];
    __syncthreads();
#pragma unroll
    for (int r = 0; r < 32; r += 8)
        VT[(size_t)(bh * DHH + d0 + ty + r) * SS + s0 + tx] = t[tx][ty + r];
}

// ---------------- GEMM: C[M][N] = A[M][K] * Bt[N][K]^T + bias ----------------
// BMx128 tile, BK=64, 4 waves (2x2), mfma 16x16x32 bf16.
// Staging via global_load_lds(16B) into LINEAR LDS; T2 swizzle applied by
// pre-swizzling the global source column and XOR-ing the ds_read column
// (rule #21: same involution both sides).
template<int BM, bool OUT_BF16, bool RELU>
__global__ __launch_bounds__(256, 3) void gemm_bt_kernel(
    const u16* __restrict__ A, const u16* __restrict__ Bt,
    const float* __restrict__ bias, void* __restrict__ Cv,
    int M, int N, int K)
{
    constexpr int MR = BM / 32;  // 16x16 fragment rows per wave
    __shared__ __attribute__((aligned(16))) u16 As[BM][64];
    __shared__ __attribute__((aligned(16))) u16 Bs[128][64];
    const int tid = threadIdx.x;
    const int lane = tid & 63, wid = tid >> 6;
    const int wr = wid >> 1, wc = wid & 1;
    const int m0 = blockIdx.y * BM, n0 = blockIdx.x * 128;
    const int arow = lane & 15;
    const int kseg = (lane >> 4) * 8;
    const int srow = lane >> 3;                 // row within 8-row chunk
    const int scol = ((lane & 7) ^ srow) * 8;   // inverse-swizzled source col
    const int rswz = (arow & 7) << 3;           // read-side XOR
    const f32x4 z4 = {0.f, 0.f, 0.f, 0.f};

    f32x4 acc[MR][4];
#pragma unroll
    for (int i = 0; i < MR; ++i)
#pragma unroll
        for (int j = 0; j < 4; ++j) acc[i][j] = z4;

    for (int kt = 0; kt < K; kt += 64) {
        __syncthreads();
#pragma unroll
        for (int i = 0; i < MR; ++i) {
            int ch = wid + i * 4;  // 1KB chunk = 8 rows x 64 cols
            async16(&A[(size_t)(m0 + ch * 8 + srow) * K + kt + scol], &As[ch * 8][0]);
        }
#pragma unroll
        for (int i = 0; i < 4; ++i) {
            int ch = wid + i * 4;
            async16(&Bt[(size_t)(n0 + ch * 8 + srow) * K + kt + scol], &Bs[ch * 8][0]);
        }
        __syncthreads();
#pragma unroll
        for (int ks = 0; ks < 2; ++ks) {
            const int cswz = (ks * 32 + kseg) ^ rswz;
            bf16x8 af[MR], bfr[4];
#pragma unroll
            for (int mi = 0; mi < MR; ++mi)
                af[mi] = *reinterpret_cast<const bf16x8*>(&As[wr * (BM / 2) + mi * 16 + arow][cswz]);
#pragma unroll
            for (int ni = 0; ni < 4; ++ni)
                bfr[ni] = *reinterpret_cast<const bf16x8*>(&Bs[wc * 64 + ni * 16 + arow][cswz]);
#pragma unroll
            for (int mi = 0; mi < MR; ++mi)
#pragma unroll
                for (int ni = 0; ni < 4; ++ni)
                    acc[mi][ni] = __builtin_amdgcn_mfma_f32_16x16x32_bf16(af[mi], bfr[ni], acc[mi][ni], 0, 0, 0);
        }
    }
    const int rrow = (lane >> 4) * 4;
#pragma unroll
    for (int mi = 0; mi < MR; ++mi)
#pragma unroll
        for (int ni = 0; ni < 4; ++ni) {
            int col = n0 + wc * 64 + ni * 16 + arow;
            float bv = bias[col];
#pragma unroll
            for (int r = 0; r < 4; ++r) {
                int row = m0 + wr * (BM / 2) + mi * 16 + rrow + r;
                float v = acc[mi][ni][r] + bv;
                if (RELU) v = fmaxf(v, 0.f);
                if (OUT_BF16) ((u16*)Cv)[(size_t)row * N + col] = f2b(v);
                else          ((float*)Cv)[(size_t)row * N + col] = v;
            }
        }
}

// ---------------- flash attention ----------------
// grid: (S/128, B*H); 256 threads = 4 waves; each wave owns 32 q-rows.
__global__ __launch_bounds__(256, 2) void flash_attn_kernel(
    const u16* __restrict__ Q, int ldq, const u16* __restrict__ Kp, int ldk,
    const u16* __restrict__ VT, u16* __restrict__ O,
    const int* __restrict__ vlens, int causal)
{
    __shared__ __attribute__((aligned(16))) u16 Ks[128][64];
    __shared__ __attribute__((aligned(16))) u16 Vs[64][128];
    __shared__ __attribute__((aligned(16))) u16 Ps[128][136];
    const int tid = threadIdx.x, lane = tid & 63, wid = tid >> 6;
    const int qb = blockIdx.x, bh = blockIdx.y;
    const int b = bh >> 4, h = bh & 15;
    const int q0 = qb * 128;
    const int arow = lane & 15;
    const int kseg = (lane >> 4) * 8;
    const int rrow = (lane >> 4) * 4;
    const int srow = lane >> 3;
    const int scol = ((lane & 7) ^ srow) * 8;
    const int vrow = lane >> 4;                            // 0..3 (row within 4-row V chunk)
    const int vscol = ((lane & 15) ^ (wid * 4 + vrow)) * 8; // V chunk index & 3 == wid
    const int rswz = (arow & 7) << 3;
    const int vswz = arow << 3;
    const f32x4 z4 = {0.f, 0.f, 0.f, 0.f};

    bf16x8 qf[2][2];
#pragma unroll
    for (int mi = 0; mi < 2; ++mi)
#pragma unroll
        for (int ks = 0; ks < 2; ++ks)
            qf[mi][ks] = *reinterpret_cast<const bf16x8*>(
                &Q[(size_t)(b * SS + q0 + wid * 32 + mi * 16 + arow) * ldq + h * DHH + ks * 32 + kseg]);

    float m_run[2][4], l_run[2][4];
    f32x4 o[2][4];
#pragma unroll
    for (int mi = 0; mi < 2; ++mi) {
#pragma unroll
        for (int r = 0; r < 4; ++r) { m_run[mi][r] = -3e38f; l_run[mi][r] = 0.f; }
#pragma unroll
        for (int nd = 0; nd < 4; ++nd) o[mi][nd] = z4;
    }

    int vl = causal ? SS : vlens[b];
    int ntiles = causal ? (qb + 1) : ((vl + 127) >> 7);

    for (int kt = 0; kt < ntiles; ++kt) {
        const int kv0 = kt * 128;
        __syncthreads();
#pragma unroll
        for (int i = 0; i < 4; ++i) {
            int ch = wid + i * 4;
            async16(&Kp[(size_t)(b * SS + kv0 + ch * 8 + srow) * ldk + h * DHH + scol], &Ks[ch * 8][0]);
        }
#pragma unroll
        for (int i = 0; i < 4; ++i) {
            int cv = wid + i * 4;
            async16(&VT[(size_t)(bh * DHH + cv * 4 + vrow) * SS + kv0 + vscol], &Vs[cv * 4][0]);
        }
        __syncthreads();

        // S = Q K^T
        f32x4 s[2][8];
#pragma unroll
        for (int mi = 0; mi < 2; ++mi)
#pragma unroll
            for (int ni = 0; ni < 8; ++ni) s[mi][ni] = z4;
#pragma unroll
        for (int ks = 0; ks < 2; ++ks) {
            const int cswz = (ks * 32 + kseg) ^ rswz;
            bf16x8 kf[8];
#pragma unroll
            for (int ni = 0; ni < 8; ++ni)
                kf[ni] = *reinterpret_cast<const bf16x8*>(&Ks[ni * 16 + arow][cswz]);
#pragma unroll
            for (int mi = 0; mi < 2; ++mi)
#pragma unroll
                for (int ni = 0; ni < 8; ++ni)
                    s[mi][ni] = __builtin_amdgcn_mfma_f32_16x16x32_bf16(qf[mi][ks], kf[ni], s[mi][ni], 0, 0, 0);
        }

        bool domask = causal ? (kt == qb) : (kv0 + 128 > vl);
#pragma unroll
        for (int mi = 0; mi < 2; ++mi)
#pragma unroll
            for (int ni = 0; ni < 8; ++ni)
#pragma unroll
                for (int r = 0; r < 4; ++r) {
                    float v = s[mi][ni][r] * 0.125f;
                    if (domask) {
                        int rg = q0 + wid * 32 + mi * 16 + rrow + r;
                        int cg = kv0 + ni * 16 + arow;
                        bool keep = causal ? (cg <= rg) : (cg < vl);
                        if (!keep) v = NEGV;
                    }
                    s[mi][ni][r] = v;
                }

        float corr[2][4];
#pragma unroll
        for (int mi = 0; mi < 2; ++mi)
#pragma unroll
            for (int r = 0; r < 4; ++r) {
                float tm = -3e38f;
#pragma unroll
                for (int ni = 0; ni < 8; ++ni) tm = fmaxf(tm, s[mi][ni][r]);
#pragma unroll
                for (int off = 1; off < 16; off <<= 1) tm = fmaxf(tm, __shfl_xor(tm, off));
                float nm = fmaxf(m_run[mi][r], tm);
                float cr = __expf(m_run[mi][r] - nm);
                m_run[mi][r] = nm;
                corr[mi][r] = cr;
                float rs = 0.f;
#pragma unroll
                for (int ni = 0; ni < 8; ++ni) {
                    float p = __expf(s[mi][ni][r] - nm);
                    s[mi][ni][r] = p;
                    rs += p;
                }
#pragma unroll
                for (int off = 1; off < 16; off <<= 1) rs += __shfl_xor(rs, off);
                l_run[mi][r] = l_run[mi][r] * cr + rs;
            }
#pragma unroll
        for (int mi = 0; mi < 2; ++mi)
#pragma unroll
            for (int nd = 0; nd < 4; ++nd)
#pragma unroll
                for (int r = 0; r < 4; ++r) o[mi][nd][r] *= corr[mi][r];

#pragma unroll
        for (int mi = 0; mi < 2; ++mi)
#pragma unroll
            for (int ni = 0; ni < 8; ++ni)
#pragma unroll
                for (int r = 0; r < 4; ++r)
                    Ps[wid * 32 + mi * 16 + rrow + r][ni * 16 + arow] = f2b(s[mi][ni][r]);

#pragma unroll
        for (int kf_ = 0; kf_ < 4; ++kf_) {
            const int cvswz = (kf_ * 32 + kseg) ^ vswz;
            bf16x8 pa[2], vb[4];
#pragma unroll
            for (int mi = 0; mi < 2; ++mi)
                pa[mi] = *reinterpret_cast<const bf16x8*>(&Ps[wid * 32 + mi * 16 + arow][kf_ * 32 + kseg]);
#pragma unroll
            for (int nd = 0; nd < 4; ++nd)
                vb[nd] = *reinterpret_cast<const bf16x8*>(&Vs[nd * 16 + arow][cvswz]);
#pragma unroll
            for (int mi = 0; mi < 2; ++mi)
#pragma unroll
                for (int nd = 0; nd < 4; ++nd)
                    o[mi][nd] = __builtin_amdgcn_mfma_f32_16x16x32_bf16(pa[mi], vb[nd], o[mi][nd], 0, 0, 0);
        }
    }

#pragma unroll
    for (int mi = 0; mi < 2; ++mi)
#pragma unroll
        for (int r = 0; r < 4; ++r) {
            float inv = 1.f / l_run[mi][r];
            int row = q0 + wid * 32 + mi * 16 + rrow + r;
#pragma unroll
            for (int nd = 0; nd < 4; ++nd)
                O[(size_t)(b * SS + row) * DD + h * DHH + nd * 16 + arow] = f2b(o[mi][nd][r] * inv);
        }
}

// ---------------- fused add + LayerNorm ----------------
__global__ void add_ln_kernel(const float* __restrict__ A, const float* __restrict__ R,
                              const float* __restrict__ g, const float* __restrict__ be,
                              float* __restrict__ out32, u16* __restrict__ out16)
{
    __shared__ float red[4][2];
    const int row = blockIdx.x, tid = threadIdx.x;
    const size_t base = (size_t)row * DD;
    float4 va = *reinterpret_cast<const float4*>(A + base + tid * 4);
    float4 vr = *reinterpret_cast<const float4*>(R + base + tid * 4);
    float x0 = va.x + vr.x, x1 = va.y + vr.y, x2 = va.z + vr.z, x3 = va.w + vr.w;
    float s = x0 + x1 + x2 + x3;
    float q = x0 * x0 + x1 * x1 + x2 * x2 + x3 * x3;
#pragma unroll
    for (int off = 32; off; off >>= 1) {
        s += __shfl_xor(s, off);
        q += __shfl_xor(q, off);
    }
    if ((tid & 63) == 0) { red[tid >> 6][0] = s; red[tid >> 6][1] = q; }
    __syncthreads();
    s = red[0][0] + red[1][0] + red[2][0] + red[3][0];
    q = red[0][1] + red[1][1] + red[2][1] + red[3][1];
    float mean = s * (1.f / 1024.f);
    float var = q * (1.f / 1024.f) - mean * mean;
    float rstd = rsqrtf(var + 1e-5f);
    int c = tid * 4;
    float o0 = (x0 - mean) * rstd * g[c + 0] + be[c + 0];
    float o1 = (x1 - mean) * rstd * g[c + 1] + be[c + 1];
    float o2 = (x2 - mean) * rstd * g[c + 2] + be[c + 2];
    float o3 = (x3 - mean) * rstd * g[c + 3] + be[c + 3];
    float4 ov = {o0, o1, o2, o3};
    *reinterpret_cast<float4*>(out32 + base + c) = ov;
    if (out16) {
        ushort4 hv;
        hv.x = f2b(o0); hv.y = f2b(o1); hv.z = f2b(o2); hv.w = f2b(o3);
        *reinterpret_cast<ushort4*>(out16 + base + c) = hv;
    }
}

extern "C" void kernel_launch(void* const* d_in, const int* in_sizes, int n_in,
                              void* d_out, int out_size, void* d_ws, size_t ws_size,
                              hipStream_t stream)
{
    const float* X   = (const float*)d_in[0];
    const float* ENC = (const float*)d_in[1];
    const int*   VL  = (const int*)d_in[2];
    const float* Wq1 = (const float*)d_in[3];  const float* bq1 = (const float*)d_in[4];
    const float* Wk1 = (const float*)d_in[5];  const float* bk1 = (const float*)d_in[6];
    const float* Wv1 = (const float*)d_in[7];  const float* bv1 = (const float*)d_in[8];
    const float* Wo1 = (const float*)d_in[9];  const float* bo1 = (const float*)d_in[10];
    const float* g1  = (const float*)d_in[11]; const float* be1 = (const float*)d_in[12];
    const float* Wq2 = (const float*)d_in[13]; const float* bq2 = (const float*)d_in[14];
    const float* Wk2 = (const float*)d_in[15]; const float* bk2 = (const float*)d_in[16];
    const float* Wv2 = (const float*)d_in[17]; const float* bv2 = (const float*)d_in[18];
    const float* Wo2 = (const float*)d_in[19]; const float* bo2 = (const float*)d_in[20];
    const float* g2  = (const float*)d_in[21]; const float* be2 = (const float*)d_in[22];
    const float* Wf1 = (const float*)d_in[23]; const float* bf1 = (const float*)d_in[24];
    const float* Wf2 = (const float*)d_in[25]; const float* bf2 = (const float*)d_in[26];
    const float* g3  = (const float*)d_in[27]; const float* be3 = (const float*)d_in[28];

    char* ws = (char*)d_ws;
    const size_t MB = 1024 * 1024;
    u16*   XBF  = (u16*)(ws + 0 * MB);     // 8MB; reused as Q2 output later
    u16*   ENCB = (u16*)(ws + 8 * MB);     // 8MB
    u16*   WT   = (u16*)(ws + 16 * MB);    // 8MB (reused per weight / fused weights)
    u16*   QKV  = (u16*)(ws + 24 * MB);    // 24MB [4096][3072]; reused as KV2 [4096][2048]
    u16*   VTb  = (u16*)(ws + 48 * MB);    // 8MB
    u16*   AO   = (u16*)(ws + 56 * MB);    // 8MB
    float* P32  = (float*)(ws + 64 * MB);  // 16MB
    float* Y32  = (float*)(ws + 80 * MB);  // 16MB
    u16*   YBF  = (u16*)(ws + 96 * MB);    // 8MB
    float* Z32  = (float*)(ws + 104 * MB); // 16MB
    u16*   ZBF  = (u16*)(ws + 120 * MB);   // 8MB
    u16*   HF   = (u16*)(ws + 128 * MB);   // 32MB (FFN hidden) -> ends at 160MB
    // bias concat buffers live in the tail of HF: all uses precede FFN1's HF write
    float* B1   = (float*)(ws + 156 * MB);        // 12KB (qkv bias)
    float* B2   = (float*)(ws + 156 * MB + 65536);// 8KB  (kv bias)
    (void)ws_size; (void)in_sizes; (void)n_in; (void)out_size;

    const int M = BB * SS; // 4096

    cvt_bf16_kernel<<<M * DD / 4 / 256, 256, 0, stream>>>(X, XBF, M * DD / 4);
    cvt_bf16_kernel<<<M * DD / 4 / 256, 256, 0, stream>>>(ENC, ENCB, M * DD / 4);

    // ---------- self attention (fused QKV projection, N=3072) ----------
    concat_bias_kernel<<<12, 256, 0, stream>>>(bq1, bk1, bv1, B1);
    wtrans_kernel<<<dim3(32, 32), dim3(32, 8), 0, stream>>>(Wq1, WT, DD, DD);
    wtrans_kernel<<<dim3(32, 32), dim3(32, 8), 0, stream>>>(Wk1, WT + 1024 * 1024, DD, DD);
    wtrans_kernel<<<dim3(32, 32), dim3(32, 8), 0, stream>>>(Wv1, WT + 2048 * 1024, DD, DD);
    gemm_bt_kernel<128, true, false><<<dim3(24, 32), 256, 0, stream>>>(XBF, WT, B1, QKV, M, 3072, DD);
    vtrans_kernel<<<dim3(32, 2, 64), dim3(32, 8), 0, stream>>>(QKV + 2048, 3072, VTb);
    flash_attn_kernel<<<dim3(8, 64), 256, 0, stream>>>(QKV, 3072, QKV + 1024, 3072, VTb, AO, VL, 1);
    wtrans_kernel<<<dim3(32, 32), dim3(32, 8), 0, stream>>>(Wo1, WT, DD, DD);
    gemm_bt_kernel<64, false, false><<<dim3(8, 64), 256, 0, stream>>>(AO, WT, bo1, P32, M, DD, DD);
    add_ln_kernel<<<M, 256, 0, stream>>>(P32, X, g1, be1, Y32, YBF);

    // ---------- cross attention (fused KV projection, N=2048) ----------
    wtrans_kernel<<<dim3(32, 32), dim3(32, 8), 0, stream>>>(Wq2, WT, DD, DD);
    gemm_bt_kernel<64, true, false><<<dim3(8, 64), 256, 0, stream>>>(YBF, WT, bq2, XBF, M, DD, DD);
    concat_bias_kernel<<<8, 256, 0, stream>>>(bk2, bv2, bv2, B2);
    wtrans_kernel<<<dim3(32, 32), dim3(32, 8), 0, stream>>>(Wk2, WT, DD, DD);
    wtrans_kernel<<<dim3(32, 32), dim3(32, 8), 0, stream>>>(Wv2, WT + 1024 * 1024, DD, DD);
    gemm_bt_kernel<128, true, false><<<dim3(16, 32), 256, 0, stream>>>(ENCB, WT, B2, QKV, M, 2048, DD);
    vtrans_kernel<<<dim3(32, 2, 64), dim3(32, 8), 0, stream>>>(QKV + 1024, 2048, VTb);
    flash_attn_kernel<<<dim3(8, 64), 256, 0, stream>>>(XBF, 1024, QKV, 2048, VTb, AO, VL, 0);
    wtrans_kernel<<<dim3(32, 32), dim3(32, 8), 0, stream>>>(Wo2, WT, DD, DD);
    gemm_bt_kernel<64, false, false><<<dim3(8, 64), 256, 0, stream>>>(AO, WT, bo2, P32, M, DD, DD);
    add_ln_kernel<<<M, 256, 0, stream>>>(P32, Y32, g2, be2, Z32, ZBF);

    // ---------- FFN ----------
    wtrans_kernel<<<dim3(128, 32), dim3(32, 8), 0, stream>>>(Wf1, WT, DD, FF);
    gemm_bt_kernel<128, true, true><<<dim3(32, 32), 256, 0, stream>>>(ZBF, WT, bf1, HF, M, FF, DD);
    wtrans_kernel<<<dim3(32, 128), dim3(32, 8), 0, stream>>>(Wf2, WT, FF, DD);
    gemm_bt_kernel<64, false, false><<<dim3(8, 64), 256, 0, stream>>>(HF, WT, bf2, P32, M, DD, FF);
    add_ln_kernel<<<M, 256, 0, stream>>>(P32, Z32, g3, be3, (float*)d_out, nullptr);
}

// Round 4
// 385.710 us; speedup vs baseline: 1.4324x; 1.0918x over previous
//
#include <hip/hip_runtime.h>
#include <stdint.h>

typedef unsigned short u16;
typedef __bf16 bf16x8 __attribute__((ext_vector_type(8)));
typedef float f32x4 __attribute__((ext_vector_type(4)));

#define BB 4
#define SS 1024
#define DD 1024
#define HH 16
#define DHH 64
#define FF 4096
#define NEGV -1000000.0f

__device__ __forceinline__ u16 f2b(float f) {
    uint32_t u = __float_as_uint(f);
    u += 0x7fff + ((u >> 16) & 1);
    return (u16)(u >> 16);
}

// async global->LDS, 16B per lane. LDS dest is wave-uniform base + lane*16;
// global src is per-lane (pre-swizzled for swizzled LDS layouts).
__device__ __forceinline__ void async16(const void* gp, void* lp) {
    auto g = reinterpret_cast<const __attribute__((address_space(1))) uint32_t*>(
        reinterpret_cast<uintptr_t>(gp));
    auto l = reinterpret_cast<__attribute__((address_space(3))) uint32_t*>(
        reinterpret_cast<uintptr_t>(lp));
    __builtin_amdgcn_global_load_lds(g, l, 16, 0, 0);
}

// ---------------- fp32 -> bf16 convert ----------------
__global__ void cvt_bf16_kernel(const float* __restrict__ in, u16* __restrict__ out, int n4) {
    int i = blockIdx.x * blockDim.x + threadIdx.x;
    if (i >= n4) return;
    float4 v = reinterpret_cast<const float4*>(in)[i];
    ushort4 o;
    o.x = f2b(v.x); o.y = f2b(v.y); o.z = f2b(v.z); o.w = f2b(v.w);
    reinterpret_cast<ushort4*>(out)[i] = o;
}

// ---------------- bias concat ----------------
__global__ void concat_bias_kernel(const float* __restrict__ a, const float* __restrict__ b,
                                   const float* __restrict__ c, float* __restrict__ out) {
    int i = blockIdx.x * 256 + threadIdx.x;
    float v;
    if (i < 1024) v = a[i];
    else if (i < 2048) v = b[i - 1024];
    else v = c[i - 2048];
    out[i] = v;
}

// ---------------- weight transpose + convert: W[K][N] f32 -> Wt[N][K] bf16 ----------------
// 64x64 tile, 256 threads, float4 loads + ushort4 stores.
__global__ void wtrans_kernel(const float* __restrict__ W, u16* __restrict__ Wt, int K, int N) {
    __shared__ u16 t[64][68];
    int n0 = blockIdx.x * 64, k0 = blockIdx.y * 64;
    int tx = threadIdx.x & 15, ty = threadIdx.x >> 4;
#pragma unroll
    for (int rr = 0; rr < 4; ++rr) {
        int r = ty + rr * 16;
        float4 v = *reinterpret_cast<const float4*>(&W[(size_t)(k0 + r) * N + n0 + tx * 4]);
        ushort4 o;
        o.x = f2b(v.x); o.y = f2b(v.y); o.z = f2b(v.z); o.w = f2b(v.w);
        *reinterpret_cast<ushort4*>(&t[r][tx * 4]) = o;
    }
    __syncthreads();
#pragma unroll
    for (int rr = 0; rr < 4; ++rr) {
        int n = ty + rr * 16;
        ushort4 o;
        o.x = t[tx * 4 + 0][n];
        o.y = t[tx * 4 + 1][n];
        o.z = t[tx * 4 + 2][n];
        o.w = t[tx * 4 + 3][n];
        *reinterpret_cast<ushort4*>(&Wt[(size_t)(n0 + n) * K + k0 + tx * 4]) = o;
    }
}

// ---------------- V transpose per head ----------------
__global__ void vtrans_kernel(const u16* __restrict__ V, int ldv, u16* __restrict__ VT) {
    __shared__ u16 t[32][33];
    int bh = blockIdx.z;
    int b = bh >> 4, h = bh & 15;
    int s0 = blockIdx.x * 32, d0 = blockIdx.y * 32;
    int tx = threadIdx.x, ty = threadIdx.y;
#pragma unroll
    for (int r = 0; r < 32; r += 8)
        t[ty + r][tx] = V[(size_t)(b * SS + s0 + ty + r) * ldv + h * DHH + d0 + tx];
    __syncthreads();
#pragma unroll
    for (int r = 0; r < 32; r += 8)
        VT[(size_t)(bh * DHH + d0 + ty + r) * SS + s0 + tx] = t[tx][ty + r];
}

// ---------------- GEMM: C[M][N] = A[M][K] * Bt[N][K]^T + bias ----------------
template<int BM, bool OUT_BF16, bool RELU>
__global__ __launch_bounds__(256, 3) void gemm_bt_kernel(
    const u16* __restrict__ A, const u16* __restrict__ Bt,
    const float* __restrict__ bias, void* __restrict__ Cv,
    int M, int N, int K)
{
    constexpr int MR = BM / 32;
    __shared__ __attribute__((aligned(16))) u16 As[BM][64];
    __shared__ __attribute__((aligned(16))) u16 Bs[128][64];
    const int tid = threadIdx.x;
    const int lane = tid & 63, wid = tid >> 6;
    const int wr = wid >> 1, wc = wid & 1;
    const int m0 = blockIdx.y * BM, n0 = blockIdx.x * 128;
    const int arow = lane & 15;
    const int kseg = (lane >> 4) * 8;
    const int srow = lane >> 3;
    const int scol = ((lane & 7) ^ srow) * 8;
    const int rswz = (arow & 7) << 3;
    const f32x4 z4 = {0.f, 0.f, 0.f, 0.f};

    f32x4 acc[MR][4];
#pragma unroll
    for (int i = 0; i < MR; ++i)
#pragma unroll
        for (int j = 0; j < 4; ++j) acc[i][j] = z4;

    for (int kt = 0; kt < K; kt += 64) {
        __syncthreads();
#pragma unroll
        for (int i = 0; i < MR; ++i) {
            int ch = wid + i * 4;
            async16(&A[(size_t)(m0 + ch * 8 + srow) * K + kt + scol], &As[ch * 8][0]);
        }
#pragma unroll
        for (int i = 0; i < 4; ++i) {
            int ch = wid + i * 4;
            async16(&Bt[(size_t)(n0 + ch * 8 + srow) * K + kt + scol], &Bs[ch * 8][0]);
        }
        __syncthreads();
#pragma unroll
        for (int ks = 0; ks < 2; ++ks) {
            const int cswz = (ks * 32 + kseg) ^ rswz;
            bf16x8 af[MR], bfr[4];
#pragma unroll
            for (int mi = 0; mi < MR; ++mi)
                af[mi] = *reinterpret_cast<const bf16x8*>(&As[wr * (BM / 2) + mi * 16 + arow][cswz]);
#pragma unroll
            for (int ni = 0; ni < 4; ++ni)
                bfr[ni] = *reinterpret_cast<const bf16x8*>(&Bs[wc * 64 + ni * 16 + arow][cswz]);
#pragma unroll
            for (int mi = 0; mi < MR; ++mi)
#pragma unroll
                for (int ni = 0; ni < 4; ++ni)
                    acc[mi][ni] = __builtin_amdgcn_mfma_f32_16x16x32_bf16(af[mi], bfr[ni], acc[mi][ni], 0, 0, 0);
        }
    }
    const int rrow = (lane >> 4) * 4;
#pragma unroll
    for (int mi = 0; mi < MR; ++mi)
#pragma unroll
        for (int ni = 0; ni < 4; ++ni) {
            int col = n0 + wc * 64 + ni * 16 + arow;
            float bv = bias[col];
#pragma unroll
            for (int r = 0; r < 4; ++r) {
                int row = m0 + wr * (BM / 2) + mi * 16 + rrow + r;
                float v = acc[mi][ni][r] + bv;
                if (RELU) v = fmaxf(v, 0.f);
                if (OUT_BF16) ((u16*)Cv)[(size_t)row * N + col] = f2b(v);
                else          ((float*)Cv)[(size_t)row * N + col] = v;
            }
        }
}

// ---------------- flash attention, swapped QK^T ----------------
// grid: (S/128, B*H); 256 threads = 4 waves; wave owns 32 q-rows.
// S^T = mfma(K,Q): lane (g=lane>>4, a=lane&15) holds, for q = q0+wid*32+mi*16+a,
// P-values at kv = kv0 + ni*16 + 4g + r  -> row softmax = in-reg + 2 shfl.
__global__ __launch_bounds__(256, 2) void flash_attn_kernel(
    const u16* __restrict__ Q, int ldq, const u16* __restrict__ Kp, int ldk,
    const u16* __restrict__ VT, u16* __restrict__ O,
    const int* __restrict__ vlens, int causal)
{
    __shared__ __attribute__((aligned(16))) u16 Ks[128][64];
    __shared__ __attribute__((aligned(16))) u16 Vs[64][128];
    __shared__ __attribute__((aligned(16))) u16 Ps[128][128];  // [q][kv] — FULL 128 kv cols (r3 bug: was 64)
    const int tid = threadIdx.x, lane = tid & 63, wid = tid >> 6;
    int qb = blockIdx.x;
    const int bh = blockIdx.y;
    if (causal) qb = ((bh >> 5) & 1) ? (7 - qb) : qb;  // pair heavy+light on same CU
    const int b = bh >> 4, h = bh & 15;
    const int q0 = qb * 128;
    const int a = lane & 15;
    const int g = lane >> 4;
    const int kseg = g * 8;
    const int srow = lane >> 3;
    const int scol = ((lane & 7) ^ srow) * 8;
    const int vrow = lane >> 4;
    const int vscol = ((lane & 15) ^ (wid * 4 + vrow)) * 8;
    const int rswz = (a & 7) << 3;
    const int vswz = a << 3;
    const f32x4 z4 = {0.f, 0.f, 0.f, 0.f};

    bf16x8 qf[2][2];
#pragma unroll
    for (int mi = 0; mi < 2; ++mi)
#pragma unroll
        for (int ks = 0; ks < 2; ++ks)
            qf[mi][ks] = *reinterpret_cast<const bf16x8*>(
                &Q[(size_t)(b * SS + q0 + wid * 32 + mi * 16 + a) * ldq + h * DHH + ks * 32 + kseg]);

    float m_run[2], l_run[2];
    f32x4 o[2][4];
#pragma unroll
    for (int mi = 0; mi < 2; ++mi) {
        m_run[mi] = -3e38f; l_run[mi] = 0.f;
#pragma unroll
        for (int nd = 0; nd < 4; ++nd) o[mi][nd] = z4;
    }

    int vl = causal ? SS : vlens[b];
    int ntiles = causal ? (qb + 1) : ((vl + 127) >> 7);

    for (int kt = 0; kt < ntiles; ++kt) {
        const int kv0 = kt * 128;
        __syncthreads();
#pragma unroll
        for (int i = 0; i < 4; ++i) {
            int ch = wid + i * 4;
            async16(&Kp[(size_t)(b * SS + kv0 + ch * 8 + srow) * ldk + h * DHH + scol], &Ks[ch * 8][0]);
        }
#pragma unroll
        for (int i = 0; i < 4; ++i) {
            int cv = wid + i * 4;
            async16(&VT[(size_t)(bh * DHH + cv * 4 + vrow) * SS + kv0 + vscol], &Vs[cv * 4][0]);
        }
        __syncthreads();

        // S^T = K Q^T (A=K frag, B=Q frag)
        f32x4 st[2][8];
#pragma unroll
        for (int mi = 0; mi < 2; ++mi)
#pragma unroll
            for (int ni = 0; ni < 8; ++ni) st[mi][ni] = z4;
        __builtin_amdgcn_s_setprio(1);
#pragma unroll
        for (int ks = 0; ks < 2; ++ks) {
            const int cswz = (ks * 32 + kseg) ^ rswz;
            bf16x8 kf[8];
#pragma unroll
            for (int ni = 0; ni < 8; ++ni)
                kf[ni] = *reinterpret_cast<const bf16x8*>(&Ks[ni * 16 + a][cswz]);
#pragma unroll
            for (int mi = 0; mi < 2; ++mi)
#pragma unroll
                for (int ni = 0; ni < 8; ++ni)
                    st[mi][ni] = __builtin_amdgcn_mfma_f32_16x16x32_bf16(kf[ni], qf[mi][ks], st[mi][ni], 0, 0, 0);
        }
        __builtin_amdgcn_s_setprio(0);

        // scale + mask: lane value (mi,ni,r): q = q0+wid*32+mi*16+a, kv = kv0+ni*16+4g+r
        bool domask = causal ? (kt == qb) : (kv0 + 128 > vl);
#pragma unroll
        for (int mi = 0; mi < 2; ++mi) {
            const int qg = q0 + wid * 32 + mi * 16 + a;
#pragma unroll
            for (int ni = 0; ni < 8; ++ni)
#pragma unroll
                for (int r = 0; r < 4; ++r) {
                    float v = st[mi][ni][r] * 0.125f;
                    if (domask) {
                        int cg = kv0 + ni * 16 + 4 * g + r;
                        bool keep = causal ? (cg <= qg) : (cg < vl);
                        if (!keep) v = NEGV;
                    }
                    st[mi][ni][r] = v;
                }
        }

        // online softmax: per mi, lane owns 32 vals of one q-row
        float corr[2];
#pragma unroll
        for (int mi = 0; mi < 2; ++mi) {
            float tm = -3e38f;
#pragma unroll
            for (int ni = 0; ni < 8; ++ni)
#pragma unroll
                for (int r = 0; r < 4; ++r) tm = fmaxf(tm, st[mi][ni][r]);
            tm = fmaxf(tm, __shfl_xor(tm, 16));
            tm = fmaxf(tm, __shfl_xor(tm, 32));
            float nm = fmaxf(m_run[mi], tm);
            corr[mi] = __expf(m_run[mi] - nm);
            m_run[mi] = nm;
            float rs = 0.f;
#pragma unroll
            for (int ni = 0; ni < 8; ++ni)
#pragma unroll
                for (int r = 0; r < 4; ++r) {
                    float p = __expf(st[mi][ni][r] - nm);
                    st[mi][ni][r] = p;
                    rs += p;
                }
            rs += __shfl_xor(rs, 16);
            rs += __shfl_xor(rs, 32);
            l_run[mi] = l_run[mi] * corr[mi] + rs;
        }

        // rescale O: o[mi][nd] rows are q = ...+4g+r -> fetch corr from lane a'=4g+r
#pragma unroll
        for (int mi = 0; mi < 2; ++mi) {
#pragma unroll
            for (int r = 0; r < 4; ++r) {
                float cr = __shfl(corr[mi], (lane & 48) + 4 * g + r);
#pragma unroll
                for (int nd = 0; nd < 4; ++nd) o[mi][nd][r] *= cr;
            }
        }

        // P -> LDS (bf16, swizzled): 4 contiguous kv per (mi,ni) -> ds_write_b64
#pragma unroll
        for (int mi = 0; mi < 2; ++mi)
#pragma unroll
            for (int ni = 0; ni < 8; ++ni) {
                uint2 pw;
                pw.x = (uint32_t)f2b(st[mi][ni][0]) | ((uint32_t)f2b(st[mi][ni][1]) << 16);
                pw.y = (uint32_t)f2b(st[mi][ni][2]) | ((uint32_t)f2b(st[mi][ni][3]) << 16);
                int prow = wid * 32 + mi * 16 + a;
                int pcol = (ni * 16 + 4 * g) ^ rswz;
                *reinterpret_cast<uint2*>(&Ps[prow][pcol]) = pw;
            }

        // O += P V  (wave-private P rows: no barrier needed)
        __builtin_amdgcn_s_setprio(1);
#pragma unroll
        for (int kf_ = 0; kf_ < 4; ++kf_) {
            const int pswz = (kf_ * 32 + kseg) ^ rswz;
            const int cvswz = (kf_ * 32 + kseg) ^ vswz;
            bf16x8 pa[2], vb[4];
#pragma unroll
            for (int mi = 0; mi < 2; ++mi)
                pa[mi] = *reinterpret_cast<const bf16x8*>(&Ps[wid * 32 + mi * 16 + a][pswz]);
#pragma unroll
            for (int nd = 0; nd < 4; ++nd)
                vb[nd] = *reinterpret_cast<const bf16x8*>(&Vs[nd * 16 + a][cvswz]);
#pragma unroll
            for (int mi = 0; mi < 2; ++mi)
#pragma unroll
                for (int nd = 0; nd < 4; ++nd)
                    o[mi][nd] = __builtin_amdgcn_mfma_f32_16x16x32_bf16(pa[mi], vb[nd], o[mi][nd], 0, 0, 0);
        }
        __builtin_amdgcn_s_setprio(0);
    }

    // epilogue: row q = q0+wid*32+mi*16+4g+r, d = nd*16+a
#pragma unroll
    for (int mi = 0; mi < 2; ++mi) {
        float il = 1.f / l_run[mi];
#pragma unroll
        for (int r = 0; r < 4; ++r) {
            float ilr = __shfl(il, (lane & 48) + 4 * g + r);
            int row = q0 + wid * 32 + mi * 16 + 4 * g + r;
#pragma unroll
            for (int nd = 0; nd < 4; ++nd)
                O[(size_t)(b * SS + row) * DD + h * DHH + nd * 16 + a] = f2b(o[mi][nd][r] * ilr);
        }
    }
}

// ---------------- fused add + LayerNorm ----------------
__global__ void add_ln_kernel(const float* __restrict__ A, const float* __restrict__ R,
                              const float* __restrict__ g, const float* __restrict__ be,
                              float* __restrict__ out32, u16* __restrict__ out16)
{
    __shared__ float red[4][2];
    const int row = blockIdx.x, tid = threadIdx.x;
    const size_t base = (size_t)row * DD;
    float4 va = *reinterpret_cast<const float4*>(A + base + tid * 4);
    float4 vr = *reinterpret_cast<const float4*>(R + base + tid * 4);
    float x0 = va.x + vr.x, x1 = va.y + vr.y, x2 = va.z + vr.z, x3 = va.w + vr.w;
    float s = x0 + x1 + x2 + x3;
    float q = x0 * x0 + x1 * x1 + x2 * x2 + x3 * x3;
#pragma unroll
    for (int off = 32; off; off >>= 1) {
        s += __shfl_xor(s, off);
        q += __shfl_xor(q, off);
    }
    if ((tid & 63) == 0) { red[tid >> 6][0] = s; red[tid >> 6][1] = q; }
    __syncthreads();
    s = red[0][0] + red[1][0] + red[2][0] + red[3][0];
    q = red[0][1] + red[1][1] + red[2][1] + red[3][1];
    float mean = s * (1.f / 1024.f);
    float var = q * (1.f / 1024.f) - mean * mean;
    float rstd = rsqrtf(var + 1e-5f);
    int c = tid * 4;
    float o0 = (x0 - mean) * rstd * g[c + 0] + be[c + 0];
    float o1 = (x1 - mean) * rstd * g[c + 1] + be[c + 1];
    float o2 = (x2 - mean) * rstd * g[c + 2] + be[c + 2];
    float o3 = (x3 - mean) * rstd * g[c + 3] + be[c + 3];
    float4 ov = {o0, o1, o2, o3};
    *reinterpret_cast<float4*>(out32 + base + c) = ov;
    if (out16) {
        ushort4 hv;
        hv.x = f2b(o0); hv.y = f2b(o1); hv.z = f2b(o2); hv.w = f2b(o3);
        *reinterpret_cast<ushort4*>(out16 + base + c) = hv;
    }
}

extern "C" void kernel_launch(void* const* d_in, const int* in_sizes, int n_in,
                              void* d_out, int out_size, void* d_ws, size_t ws_size,
                              hipStream_t stream)
{
    const float* X   = (const float*)d_in[0];
    const float* ENC = (const float*)d_in[1];
    const int*   VL  = (const int*)d_in[2];
    const float* Wq1 = (const float*)d_in[3];  const float* bq1 = (const float*)d_in[4];
    const float* Wk1 = (const float*)d_in[5];  const float* bk1 = (const float*)d_in[6];
    const float* Wv1 = (const float*)d_in[7];  const float* bv1 = (const float*)d_in[8];
    const float* Wo1 = (const float*)d_in[9];  const float* bo1 = (const float*)d_in[10];
    const float* g1  = (const float*)d_in[11]; const float* be1 = (const float*)d_in[12];
    const float* Wq2 = (const float*)d_in[13]; const float* bq2 = (const float*)d_in[14];
    const float* Wk2 = (const float*)d_in[15]; const float* bk2 = (const float*)d_in[16];
    const float* Wv2 = (const float*)d_in[17]; const float* bv2 = (const float*)d_in[18];
    const float* Wo2 = (const float*)d_in[19]; const float* bo2 = (const float*)d_in[20];
    const float* g2  = (const float*)d_in[21]; const float* be2 = (const float*)d_in[22];
    const float* Wf1 = (const float*)d_in[23]; const float* bf1 = (const float*)d_in[24];
    const float* Wf2 = (const float*)d_in[25]; const float* bf2 = (const float*)d_in[26];
    const float* g3  = (const float*)d_in[27]; const float* be3 = (const float*)d_in[28];

    char* ws = (char*)d_ws;
    const size_t MB = 1024 * 1024;
    u16*   XBF  = (u16*)(ws + 0 * MB);
    u16*   ENCB = (u16*)(ws + 8 * MB);
    u16*   WT   = (u16*)(ws + 16 * MB);
    u16*   QKV  = (u16*)(ws + 24 * MB);
    u16*   VTb  = (u16*)(ws + 48 * MB);
    u16*   AO   = (u16*)(ws + 56 * MB);
    float* P32  = (float*)(ws + 64 * MB);
    float* Y32  = (float*)(ws + 80 * MB);
    u16*   YBF  = (u16*)(ws + 96 * MB);
    float* Z32  = (float*)(ws + 104 * MB);
    u16*   ZBF  = (u16*)(ws + 120 * MB);
    u16*   HF   = (u16*)(ws + 128 * MB);
    float* B1   = (float*)(ws + 156 * MB);
    float* B2   = (float*)(ws + 156 * MB + 65536);
    (void)ws_size; (void)in_sizes; (void)n_in; (void)out_size;

    const int M = BB * SS;

    cvt_bf16_kernel<<<M * DD / 4 / 256, 256, 0, stream>>>(X, XBF, M * DD / 4);
    cvt_bf16_kernel<<<M * DD / 4 / 256, 256, 0, stream>>>(ENC, ENCB, M * DD / 4);

    // ---------- self attention (fused QKV projection, N=3072) ----------
    concat_bias_kernel<<<12, 256, 0, stream>>>(bq1, bk1, bv1, B1);
    wtrans_kernel<<<dim3(16, 16), 256, 0, stream>>>(Wq1, WT, DD, DD);
    wtrans_kernel<<<dim3(16, 16), 256, 0, stream>>>(Wk1, WT + 1024 * 1024, DD, DD);
    wtrans_kernel<<<dim3(16, 16), 256, 0, stream>>>(Wv1, WT + 2048 * 1024, DD, DD);
    gemm_bt_kernel<128, true, false><<<dim3(24, 32), 256, 0, stream>>>(XBF, WT, B1, QKV, M, 3072, DD);
    vtrans_kernel<<<dim3(32, 2, 64), dim3(32, 8), 0, stream>>>(QKV + 2048, 3072, VTb);
    flash_attn_kernel<<<dim3(8, 64), 256, 0, stream>>>(QKV, 3072, QKV + 1024, 3072, VTb, AO, VL, 1);
    wtrans_kernel<<<dim3(16, 16), 256, 0, stream>>>(Wo1, WT, DD, DD);
    gemm_bt_kernel<64, false, false><<<dim3(8, 64), 256, 0, stream>>>(AO, WT, bo1, P32, M, DD, DD);
    add_ln_kernel<<<M, 256, 0, stream>>>(P32, X, g1, be1, Y32, YBF);

    // ---------- cross attention (fused KV projection, N=2048) ----------
    wtrans_kernel<<<dim3(16, 16), 256, 0, stream>>>(Wq2, WT, DD, DD);
    gemm_bt_kernel<64, true, false><<<dim3(8, 64), 256, 0, stream>>>(YBF, WT, bq2, XBF, M, DD, DD);
    concat_bias_kernel<<<8, 256, 0, stream>>>(bk2, bv2, bv2, B2);
    wtrans_kernel<<<dim3(16, 16), 256, 0, stream>>>(Wk2, WT, DD, DD);
    wtrans_kernel<<<dim3(16, 16), 256, 0, stream>>>(Wv2, WT + 1024 * 1024, DD, DD);
    gemm_bt_kernel<128, true, false><<<dim3(16, 32), 256, 0, stream>>>(ENCB, WT, B2, QKV, M, 2048, DD);
    vtrans_kernel<<<dim3(32, 2, 64), dim3(32, 8), 0, stream>>>(QKV + 1024, 2048, VTb);
    flash_attn_kernel<<<dim3(8, 64), 256, 0, stream>>>(XBF, 1024, QKV, 2048, VTb, AO, VL, 0);
    wtrans_kernel<<<dim3(16, 16), 256, 0, stream>>>(Wo2, WT, DD, DD);
    gemm_bt_kernel<64, false, false><<<dim3(8, 64), 256, 0, stream>>>(AO, WT, bo2, P32, M, DD, DD);
    add_ln_kernel<<<M, 256, 0, stream>>>(P32, Y32, g2, be2, Z32, ZBF);

    // ---------- FFN ----------
    wtrans_kernel<<<dim3(64, 16), 256, 0, stream>>>(Wf1, WT, DD, FF);
    gemm_bt_kernel<128, true, true><<<dim3(32, 32), 256, 0, stream>>>(ZBF, WT, bf1, HF, M, FF, DD);
    wtrans_kernel<<<dim3(16, 64), 256, 0, stream>>>(Wf2, WT, FF, DD);
    gemm_bt_kernel<64, false, false><<<dim3(8, 64), 256, 0, stream>>>(HF, WT, bf2, P32, M, DD, FF);
    add_ln_kernel<<<M, 256, 0, stream>>>(P32, Z32, g3, be3, (float*)d_out, nullptr);
}

// Round 5
// 368.030 us; speedup vs baseline: 1.5012x; 1.0480x over previous
//
#include <hip/hip_runtime.h>
#include <stdint.h>

typedef unsigned short u16;
typedef __bf16 bf16x8 __attribute__((ext_vector_type(8)));
typedef float f32x4 __attribute__((ext_vector_type(4)));

#define BB 4
#define SS 1024
#define DD 1024
#define HH 16
#define DHH 64
#define FF 4096
#define NEGV -1000000.0f

__device__ __forceinline__ u16 f2b(float f) {
    uint32_t u = __float_as_uint(f);
    u += 0x7fff + ((u >> 16) & 1);
    return (u16)(u >> 16);
}

// async global->LDS, 16B per lane. LDS dest is wave-uniform base + lane*16;
// global src is per-lane (pre-swizzled for swizzled LDS layouts).
__device__ __forceinline__ void async16(const void* gp, void* lp) {
    auto g = reinterpret_cast<const __attribute__((address_space(1))) uint32_t*>(
        reinterpret_cast<uintptr_t>(gp));
    auto l = reinterpret_cast<__attribute__((address_space(3))) uint32_t*>(
        reinterpret_cast<uintptr_t>(lp));
    __builtin_amdgcn_global_load_lds(g, l, 16, 0, 0);
}

// ---------------- fp32 -> bf16 convert ----------------
__global__ void cvt_bf16_kernel(const float* __restrict__ in, u16* __restrict__ out, int n4) {
    int i = blockIdx.x * blockDim.x + threadIdx.x;
    if (i >= n4) return;
    float4 v = reinterpret_cast<const float4*>(in)[i];
    ushort4 o;
    o.x = f2b(v.x); o.y = f2b(v.y); o.z = f2b(v.z); o.w = f2b(v.w);
    reinterpret_cast<ushort4*>(out)[i] = o;
}

// ---------------- bias concat ----------------
__global__ void concat_bias_kernel(const float* __restrict__ a, const float* __restrict__ b,
                                   const float* __restrict__ c, float* __restrict__ out) {
    int i = blockIdx.x * 256 + threadIdx.x;
    float v;
    if (i < 1024) v = a[i];
    else if (i < 2048) v = b[i - 1024];
    else v = c[i - 2048];
    out[i] = v;
}

// ---------------- weight transpose + convert: W[K][N] f32 -> Wt[N][K] bf16 ----------------
__global__ void wtrans_kernel(const float* __restrict__ W, u16* __restrict__ Wt, int K, int N) {
    __shared__ u16 t[64][68];
    int n0 = blockIdx.x * 64, k0 = blockIdx.y * 64;
    int tx = threadIdx.x & 15, ty = threadIdx.x >> 4;
#pragma unroll
    for (int rr = 0; rr < 4; ++rr) {
        int r = ty + rr * 16;
        float4 v = *reinterpret_cast<const float4*>(&W[(size_t)(k0 + r) * N + n0 + tx * 4]);
        ushort4 o;
        o.x = f2b(v.x); o.y = f2b(v.y); o.z = f2b(v.z); o.w = f2b(v.w);
        *reinterpret_cast<ushort4*>(&t[r][tx * 4]) = o;
    }
    __syncthreads();
#pragma unroll
    for (int rr = 0; rr < 4; ++rr) {
        int n = ty + rr * 16;
        ushort4 o;
        o.x = t[tx * 4 + 0][n];
        o.y = t[tx * 4 + 1][n];
        o.z = t[tx * 4 + 2][n];
        o.w = t[tx * 4 + 3][n];
        *reinterpret_cast<ushort4*>(&Wt[(size_t)(n0 + n) * K + k0 + tx * 4]) = o;
    }
}

// ---------------- V transpose per head ----------------
__global__ void vtrans_kernel(const u16* __restrict__ V, int ldv, u16* __restrict__ VT) {
    __shared__ u16 t[32][33];
    int bh = blockIdx.z;
    int b = bh >> 4, h = bh & 15;
    int s0 = blockIdx.x * 32, d0 = blockIdx.y * 32;
    int tx = threadIdx.x, ty = threadIdx.y;
#pragma unroll
    for (int r = 0; r < 32; r += 8)
        t[ty + r][tx] = V[(size_t)(b * SS + s0 + ty + r) * ldv + h * DHH + d0 + tx];
    __syncthreads();
#pragma unroll
    for (int r = 0; r < 32; r += 8)
        VT[(size_t)(bh * DHH + d0 + ty + r) * SS + s0 + tx] = t[tx][ty + r];
}

// ---------------- GEMM: C[M][N] = A[M][K] * Bt[N][K]^T + bias ----------------
// grid = (M/BM, N/128 [, KSPLIT]); m-major x => per-XCD A-slice is L2-resident.
// KSPLIT>1: block kz covers K/KSPLIT cols, writes fp32 partial at Cv + kz*M*N;
// bias only on kz==0 (reduction fused in add_ln).
template<int BM, bool OUT_BF16, bool RELU, int KSPLIT = 1>
__global__ __launch_bounds__(256, 3) void gemm_bt_kernel(
    const u16* __restrict__ A, const u16* __restrict__ Bt,
    const float* __restrict__ bias, void* __restrict__ Cv,
    int M, int N, int K)
{
    constexpr int MR = BM / 32;
    __shared__ __attribute__((aligned(16))) u16 As[BM][64];
    __shared__ __attribute__((aligned(16))) u16 Bs[128][64];
    const int tid = threadIdx.x;
    const int lane = tid & 63, wid = tid >> 6;
    const int wr = wid >> 1, wc = wid & 1;
    const int m0 = blockIdx.x * BM, n0 = blockIdx.y * 128;
    const int kz = (KSPLIT > 1) ? blockIdx.z : 0;
    const int Kc = K / KSPLIT;
    const int k0 = kz * Kc;
    const int arow = lane & 15;
    const int kseg = (lane >> 4) * 8;
    const int srow = lane >> 3;
    const int scol = ((lane & 7) ^ srow) * 8;
    const int rswz = (arow & 7) << 3;
    const f32x4 z4 = {0.f, 0.f, 0.f, 0.f};

    f32x4 acc[MR][4];
#pragma unroll
    for (int i = 0; i < MR; ++i)
#pragma unroll
        for (int j = 0; j < 4; ++j) acc[i][j] = z4;

    for (int kt = k0; kt < k0 + Kc; kt += 64) {
        __syncthreads();
#pragma unroll
        for (int i = 0; i < MR; ++i) {
            int ch = wid + i * 4;
            async16(&A[(size_t)(m0 + ch * 8 + srow) * K + kt + scol], &As[ch * 8][0]);
        }
#pragma unroll
        for (int i = 0; i < 4; ++i) {
            int ch = wid + i * 4;
            async16(&Bt[(size_t)(n0 + ch * 8 + srow) * K + kt + scol], &Bs[ch * 8][0]);
        }
        __syncthreads();
#pragma unroll
        for (int ks = 0; ks < 2; ++ks) {
            const int cswz = (ks * 32 + kseg) ^ rswz;
            bf16x8 af[MR], bfr[4];
#pragma unroll
            for (int mi = 0; mi < MR; ++mi)
                af[mi] = *reinterpret_cast<const bf16x8*>(&As[wr * (BM / 2) + mi * 16 + arow][cswz]);
#pragma unroll
            for (int ni = 0; ni < 4; ++ni)
                bfr[ni] = *reinterpret_cast<const bf16x8*>(&Bs[wc * 64 + ni * 16 + arow][cswz]);
#pragma unroll
            for (int mi = 0; mi < MR; ++mi)
#pragma unroll
                for (int ni = 0; ni < 4; ++ni)
                    acc[mi][ni] = __builtin_amdgcn_mfma_f32_16x16x32_bf16(af[mi], bfr[ni], acc[mi][ni], 0, 0, 0);
        }
    }
    const int rrow = (lane >> 4) * 4;
#pragma unroll
    for (int mi = 0; mi < MR; ++mi)
#pragma unroll
        for (int ni = 0; ni < 4; ++ni) {
            int col = n0 + wc * 64 + ni * 16 + arow;
            float bv = (kz == 0) ? bias[col] : 0.f;
#pragma unroll
            for (int r = 0; r < 4; ++r) {
                int row = m0 + wr * (BM / 2) + mi * 16 + rrow + r;
                float v = acc[mi][ni][r] + bv;
                if (RELU) v = fmaxf(v, 0.f);
                if (OUT_BF16) ((u16*)Cv)[(size_t)row * N + col] = f2b(v);
                else          ((float*)Cv)[(size_t)kz * M * N + (size_t)row * N + col] = v;
            }
        }
}

// ---------------- flash attention, swapped QK^T ----------------
// grid: (B*H, S/128) — bh-major x so each XCD's K/V set is ~2MB (L2-fit).
// 256 threads = 4 waves; wave owns 32 q-rows.
__global__ __launch_bounds__(256, 2) void flash_attn_kernel(
    const u16* __restrict__ Q, int ldq, const u16* __restrict__ Kp, int ldk,
    const u16* __restrict__ VT, u16* __restrict__ O,
    const int* __restrict__ vlens, int causal)
{
    __shared__ __attribute__((aligned(16))) u16 Ks[128][64];
    __shared__ __attribute__((aligned(16))) u16 Vs[64][128];
    __shared__ __attribute__((aligned(16))) u16 Ps[128][128];  // [q][kv]
    const int tid = threadIdx.x, lane = tid & 63, wid = tid >> 6;
    const int bh = blockIdx.x;
    int qb = blockIdx.y;
    if (causal) qb = (bh & 1) ? (7 - qb) : qb;  // pair heavy+light work
    const int b = bh >> 4, h = bh & 15;
    const int q0 = qb * 128;
    const int a = lane & 15;
    const int g = lane >> 4;
    const int kseg = g * 8;
    const int srow = lane >> 3;
    const int scol = ((lane & 7) ^ srow) * 8;
    const int vrow = lane >> 4;
    const int vscol = ((lane & 15) ^ (wid * 4 + vrow)) * 8;
    const int rswz = (a & 7) << 3;
    const int vswz = a << 3;
    const f32x4 z4 = {0.f, 0.f, 0.f, 0.f};

    bf16x8 qf[2][2];
#pragma unroll
    for (int mi = 0; mi < 2; ++mi)
#pragma unroll
        for (int ks = 0; ks < 2; ++ks)
            qf[mi][ks] = *reinterpret_cast<const bf16x8*>(
                &Q[(size_t)(b * SS + q0 + wid * 32 + mi * 16 + a) * ldq + h * DHH + ks * 32 + kseg]);

    float m_run[2], l_run[2];
    f32x4 o[2][4];
#pragma unroll
    for (int mi = 0; mi < 2; ++mi) {
        m_run[mi] = -3e38f; l_run[mi] = 0.f;
#pragma unroll
        for (int nd = 0; nd < 4; ++nd) o[mi][nd] = z4;
    }

    int vl = causal ? SS : vlens[b];
    int ntiles = causal ? (qb + 1) : ((vl + 127) >> 7);

    for (int kt = 0; kt < ntiles; ++kt) {
        const int kv0 = kt * 128;
        __syncthreads();
#pragma unroll
        for (int i = 0; i < 4; ++i) {
            int ch = wid + i * 4;
            async16(&Kp[(size_t)(b * SS + kv0 + ch * 8 + srow) * ldk + h * DHH + scol], &Ks[ch * 8][0]);
        }
#pragma unroll
        for (int i = 0; i < 4; ++i) {
            int cv = wid + i * 4;
            async16(&VT[(size_t)(bh * DHH + cv * 4 + vrow) * SS + kv0 + vscol], &Vs[cv * 4][0]);
        }
        __syncthreads();

        // S^T = K Q^T (A=K frag, B=Q frag)
        f32x4 st[2][8];
#pragma unroll
        for (int mi = 0; mi < 2; ++mi)
#pragma unroll
            for (int ni = 0; ni < 8; ++ni) st[mi][ni] = z4;
        __builtin_amdgcn_s_setprio(1);
#pragma unroll
        for (int ks = 0; ks < 2; ++ks) {
            const int cswz = (ks * 32 + kseg) ^ rswz;
            bf16x8 kf[8];
#pragma unroll
            for (int ni = 0; ni < 8; ++ni)
                kf[ni] = *reinterpret_cast<const bf16x8*>(&Ks[ni * 16 + a][cswz]);
#pragma unroll
            for (int mi = 0; mi < 2; ++mi)
#pragma unroll
                for (int ni = 0; ni < 8; ++ni)
                    st[mi][ni] = __builtin_amdgcn_mfma_f32_16x16x32_bf16(kf[ni], qf[mi][ks], st[mi][ni], 0, 0, 0);
        }
        __builtin_amdgcn_s_setprio(0);

        // scale + mask: lane (mi,ni,r): q = q0+wid*32+mi*16+a, kv = kv0+ni*16+4g+r
        bool domask = causal ? (kt == qb) : (kv0 + 128 > vl);
#pragma unroll
        for (int mi = 0; mi < 2; ++mi) {
            const int qg = q0 + wid * 32 + mi * 16 + a;
#pragma unroll
            for (int ni = 0; ni < 8; ++ni)
#pragma unroll
                for (int r = 0; r < 4; ++r) {
                    float v = st[mi][ni][r] * 0.125f;
                    if (domask) {
                        int cg = kv0 + ni * 16 + 4 * g + r;
                        bool keep = causal ? (cg <= qg) : (cg < vl);
                        if (!keep) v = NEGV;
                    }
                    st[mi][ni][r] = v;
                }
        }

        // online softmax: per mi, lane owns 32 vals of one q-row
        float corr[2];
#pragma unroll
        for (int mi = 0; mi < 2; ++mi) {
            float tm = -3e38f;
#pragma unroll
            for (int ni = 0; ni < 8; ++ni)
#pragma unroll
                for (int r = 0; r < 4; ++r) tm = fmaxf(tm, st[mi][ni][r]);
            tm = fmaxf(tm, __shfl_xor(tm, 16));
            tm = fmaxf(tm, __shfl_xor(tm, 32));
            float nm = fmaxf(m_run[mi], tm);
            corr[mi] = __expf(m_run[mi] - nm);
            m_run[mi] = nm;
            float rs = 0.f;
#pragma unroll
            for (int ni = 0; ni < 8; ++ni)
#pragma unroll
                for (int r = 0; r < 4; ++r) {
                    float p = __expf(st[mi][ni][r] - nm);
                    st[mi][ni][r] = p;
                    rs += p;
                }
            rs += __shfl_xor(rs, 16);
            rs += __shfl_xor(rs, 32);
            l_run[mi] = l_run[mi] * corr[mi] + rs;
        }

        // rescale O: o[mi][nd] rows are q = ...+4g+r -> fetch corr from lane 4g+r
#pragma unroll
        for (int mi = 0; mi < 2; ++mi) {
#pragma unroll
            for (int r = 0; r < 4; ++r) {
                float cr = __shfl(corr[mi], (lane & 48) + 4 * g + r);
#pragma unroll
                for (int nd = 0; nd < 4; ++nd) o[mi][nd][r] *= cr;
            }
        }

        // P -> LDS (bf16, swizzled): 4 contiguous kv -> ds_write_b64
#pragma unroll
        for (int mi = 0; mi < 2; ++mi)
#pragma unroll
            for (int ni = 0; ni < 8; ++ni) {
                uint2 pw;
                pw.x = (uint32_t)f2b(st[mi][ni][0]) | ((uint32_t)f2b(st[mi][ni][1]) << 16);
                pw.y = (uint32_t)f2b(st[mi][ni][2]) | ((uint32_t)f2b(st[mi][ni][3]) << 16);
                int prow = wid * 32 + mi * 16 + a;
                int pcol = (ni * 16 + 4 * g) ^ rswz;
                *reinterpret_cast<uint2*>(&Ps[prow][pcol]) = pw;
            }

        // O += P V  (wave-private P rows: no barrier needed)
        __builtin_amdgcn_s_setprio(1);
#pragma unroll
        for (int kf_ = 0; kf_ < 4; ++kf_) {
            const int pswz = (kf_ * 32 + kseg) ^ rswz;
            const int cvswz = (kf_ * 32 + kseg) ^ vswz;
            bf16x8 pa[2], vb[4];
#pragma unroll
            for (int mi = 0; mi < 2; ++mi)
                pa[mi] = *reinterpret_cast<const bf16x8*>(&Ps[wid * 32 + mi * 16 + a][pswz]);
#pragma unroll
            for (int nd = 0; nd < 4; ++nd)
                vb[nd] = *reinterpret_cast<const bf16x8*>(&Vs[nd * 16 + a][cvswz]);
#pragma unroll
            for (int mi = 0; mi < 2; ++mi)
#pragma unroll
                for (int nd = 0; nd < 4; ++nd)
                    o[mi][nd] = __builtin_amdgcn_mfma_f32_16x16x32_bf16(pa[mi], vb[nd], o[mi][nd], 0, 0, 0);
        }
        __builtin_amdgcn_s_setprio(0);
    }

    // epilogue: row q = q0+wid*32+mi*16+4g+r, d = nd*16+a
#pragma unroll
    for (int mi = 0; mi < 2; ++mi) {
        float il = 1.f / l_run[mi];
#pragma unroll
        for (int r = 0; r < 4; ++r) {
            float ilr = __shfl(il, (lane & 48) + 4 * g + r);
            int row = q0 + wid * 32 + mi * 16 + 4 * g + r;
#pragma unroll
            for (int nd = 0; nd < 4; ++nd)
                O[(size_t)(b * SS + row) * DD + h * DHH + nd * 16 + a] = f2b(o[mi][nd][r] * ilr);
        }
    }
}

// ---------------- fused (A + A2) + R add + LayerNorm (split-K reduce fused) ----------------
__global__ void add_ln_kernel(const float* __restrict__ A, const float* __restrict__ A2,
                              const float* __restrict__ R,
                              const float* __restrict__ g, const float* __restrict__ be,
                              float* __restrict__ out32, u16* __restrict__ out16)
{
    __shared__ float red[4][2];
    const int row = blockIdx.x, tid = threadIdx.x;
    const size_t base = (size_t)row * DD;
    float4 va = *reinterpret_cast<const float4*>(A + base + tid * 4);
    float4 vb = *reinterpret_cast<const float4*>(A2 + base + tid * 4);
    float4 vr = *reinterpret_cast<const float4*>(R + base + tid * 4);
    float x0 = va.x + vb.x + vr.x, x1 = va.y + vb.y + vr.y;
    float x2 = va.z + vb.z + vr.z, x3 = va.w + vb.w + vr.w;
    float s = x0 + x1 + x2 + x3;
    float q = x0 * x0 + x1 * x1 + x2 * x2 + x3 * x3;
#pragma unroll
    for (int off = 32; off; off >>= 1) {
        s += __shfl_xor(s, off);
        q += __shfl_xor(q, off);
    }
    if ((tid & 63) == 0) { red[tid >> 6][0] = s; red[tid >> 6][1] = q; }
    __syncthreads();
    s = red[0][0] + red[1][0] + red[2][0] + red[3][0];
    q = red[0][1] + red[1][1] + red[2][1] + red[3][1];
    float mean = s * (1.f / 1024.f);
    float var = q * (1.f / 1024.f) - mean * mean;
    float rstd = rsqrtf(var + 1e-5f);
    int c = tid * 4;
    float o0 = (x0 - mean) * rstd * g[c + 0] + be[c + 0];
    float o1 = (x1 - mean) * rstd * g[c + 1] + be[c + 1];
    float o2 = (x2 - mean) * rstd * g[c + 2] + be[c + 2];
    float o3 = (x3 - mean) * rstd * g[c + 3] + be[c + 3];
    float4 ov = {o0, o1, o2, o3};
    *reinterpret_cast<float4*>(out32 + base + c) = ov;
    if (out16) {
        ushort4 hv;
        hv.x = f2b(o0); hv.y = f2b(o1); hv.z = f2b(o2); hv.w = f2b(o3);
        *reinterpret_cast<ushort4*>(out16 + base + c) = hv;
    }
}

extern "C" void kernel_launch(void* const* d_in, const int* in_sizes, int n_in,
                              void* d_out, int out_size, void* d_ws, size_t ws_size,
                              hipStream_t stream)
{
    const float* X   = (const float*)d_in[0];
    const float* ENC = (const float*)d_in[1];
    const int*   VL  = (const int*)d_in[2];
    const float* Wq1 = (const float*)d_in[3];  const float* bq1 = (const float*)d_in[4];
    const float* Wk1 = (const float*)d_in[5];  const float* bk1 = (const float*)d_in[6];
    const float* Wv1 = (const float*)d_in[7];  const float* bv1 = (const float*)d_in[8];
    const float* Wo1 = (const float*)d_in[9];  const float* bo1 = (const float*)d_in[10];
    const float* g1  = (const float*)d_in[11]; const float* be1 = (const float*)d_in[12];
    const float* Wq2 = (const float*)d_in[13]; const float* bq2 = (const float*)d_in[14];
    const float* Wk2 = (const float*)d_in[15]; const float* bk2 = (const float*)d_in[16];
    const float* Wv2 = (const float*)d_in[17]; const float* bv2 = (const float*)d_in[18];
    const float* Wo2 = (const float*)d_in[19]; const float* bo2 = (const float*)d_in[20];
    const float* g2  = (const float*)d_in[21]; const float* be2 = (const float*)d_in[22];
    const float* Wf1 = (const float*)d_in[23]; const float* bf1 = (const float*)d_in[24];
    const float* Wf2 = (const float*)d_in[25]; const float* bf2 = (const float*)d_in[26];
    const float* g3  = (const float*)d_in[27]; const float* be3 = (const float*)d_in[28];

    char* ws = (char*)d_ws;
    const size_t MB = 1024 * 1024;
    // layout (liveness-checked):
    u16*   XBF  = (u16*)(ws + 0 * MB);    // 8MB  X bf16; reused as Q2 output
    u16*   ENCB = (u16*)(ws + 8 * MB);    // 8MB
    u16*   WT   = (u16*)(ws + 16 * MB);   // 8MB  transposed weights (reused)
    u16*   QKV  = (u16*)(ws + 24 * MB);   // 24MB self QKV; then KV2 (16MB); then HF (24-56)
    u16*   HF   = (u16*)(ws + 24 * MB);   // 32MB FFN hidden (over dead QKV+VTb)
    u16*   VTb  = (u16*)(ws + 48 * MB);   // 8MB
    u16*   AO   = (u16*)(ws + 56 * MB);   // 8MB
    float* P32  = (float*)(ws + 64 * MB); // 32MB: two 16MB split-K partials
    float* Y32  = (float*)(ws + 96 * MB); // 16MB
    u16*   YBF  = (u16*)(ws + 112 * MB);  // 8MB
    float* Z32  = (float*)(ws + 120 * MB);// 16MB
    u16*   ZBF  = (u16*)(ws + 136 * MB);  // 8MB
    float* B1   = (float*)(ws + 144 * MB);            // 12KB qkv bias
    float* B2   = (float*)(ws + 144 * MB + 65536);    // 8KB kv bias
    (void)ws_size; (void)in_sizes; (void)n_in; (void)out_size;

    const int M = BB * SS; // 4096
    const size_t MN = (size_t)M * DD;

    cvt_bf16_kernel<<<M * DD / 4 / 256, 256, 0, stream>>>(X, XBF, M * DD / 4);
    cvt_bf16_kernel<<<M * DD / 4 / 256, 256, 0, stream>>>(ENC, ENCB, M * DD / 4);

    // ---------- self attention (fused QKV projection, N=3072) ----------
    concat_bias_kernel<<<12, 256, 0, stream>>>(bq1, bk1, bv1, B1);
    wtrans_kernel<<<dim3(16, 16), 256, 0, stream>>>(Wq1, WT, DD, DD);
    wtrans_kernel<<<dim3(16, 16), 256, 0, stream>>>(Wk1, WT + 1024 * 1024, DD, DD);
    wtrans_kernel<<<dim3(16, 16), 256, 0, stream>>>(Wv1, WT + 2048 * 1024, DD, DD);
    gemm_bt_kernel<128, true, false><<<dim3(32, 24), 256, 0, stream>>>(XBF, WT, B1, QKV, M, 3072, DD);
    vtrans_kernel<<<dim3(32, 2, 64), dim3(32, 8), 0, stream>>>(QKV + 2048, 3072, VTb);
    flash_attn_kernel<<<dim3(64, 8), 256, 0, stream>>>(QKV, 3072, QKV + 1024, 3072, VTb, AO, VL, 1);
    wtrans_kernel<<<dim3(16, 16), 256, 0, stream>>>(Wo1, WT, DD, DD);
    gemm_bt_kernel<128, false, false, 2><<<dim3(32, 8, 2), 256, 0, stream>>>(AO, WT, bo1, P32, M, DD, DD);
    add_ln_kernel<<<M, 256, 0, stream>>>(P32, P32 + MN, X, g1, be1, Y32, YBF);

    // ---------- cross attention (fused KV projection, N=2048) ----------
    wtrans_kernel<<<dim3(16, 16), 256, 0, stream>>>(Wq2, WT, DD, DD);
    gemm_bt_kernel<64, true, false><<<dim3(64, 8), 256, 0, stream>>>(YBF, WT, bq2, XBF, M, DD, DD);
    concat_bias_kernel<<<8, 256, 0, stream>>>(bk2, bv2, bv2, B2);
    wtrans_kernel<<<dim3(16, 16), 256, 0, stream>>>(Wk2, WT, DD, DD);
    wtrans_kernel<<<dim3(16, 16), 256, 0, stream>>>(Wv2, WT + 1024 * 1024, DD, DD);
    gemm_bt_kernel<128, true, false><<<dim3(32, 16), 256, 0, stream>>>(ENCB, WT, B2, QKV, M, 2048, DD);
    vtrans_kernel<<<dim3(32, 2, 64), dim3(32, 8), 0, stream>>>(QKV + 1024, 2048, VTb);
    flash_attn_kernel<<<dim3(64, 8), 256, 0, stream>>>(XBF, 1024, QKV, 2048, VTb, AO, VL, 0);
    wtrans_kernel<<<dim3(16, 16), 256, 0, stream>>>(Wo2, WT, DD, DD);
    gemm_bt_kernel<128, false, false, 2><<<dim3(32, 8, 2), 256, 0, stream>>>(AO, WT, bo2, P32, M, DD, DD);
    add_ln_kernel<<<M, 256, 0, stream>>>(P32, P32 + MN, Y32, g2, be2, Z32, ZBF);

    // ---------- FFN ----------
    wtrans_kernel<<<dim3(64, 16), 256, 0, stream>>>(Wf1, WT, DD, FF);
    gemm_bt_kernel<128, true, true><<<dim3(32, 32), 256, 0, stream>>>(ZBF, WT, bf1, HF, M, FF, DD);
    wtrans_kernel<<<dim3(16, 64), 256, 0, stream>>>(Wf2, WT, FF, DD);
    gemm_bt_kernel<128, false, false, 2><<<dim3(32, 8, 2), 256, 0, stream>>>(HF, WT, bf2, P32, M, DD, FF);
    add_ln_kernel<<<M, 256, 0, stream>>>(P32, P32 + MN, Z32, g3, be3, (float*)d_out, nullptr);
}